// Round 1
// baseline (1041.117 us; speedup 1.0000x reference)
//
#include <hip/hip_runtime.h>

#define B_ 128
#define T_ 1024
#define D_ 512
#define K_ 16

// ---------- cross-lane helpers (16-lane groups inside wave64; ds_swizzle works per-32-lane half) ----------
template<int I>
__device__ __forceinline__ float bcast16(float v) {
  // lane' = (lane & 0x10) | I  -> broadcast lane I of each 16-group
  return __int_as_float(__builtin_amdgcn_ds_swizzle(__float_as_int(v), (I << 5) | 0x10));
}
template<int M>
__device__ __forceinline__ float xshf16(float v) {
  // lane' = lane ^ M (M < 16 stays within 16-group)
  return __int_as_float(__builtin_amdgcn_ds_swizzle(__float_as_int(v), (M << 10) | 0x1F));
}
template<int M>
__device__ __forceinline__ int xshf16i(int v) {
  return __builtin_amdgcn_ds_swizzle(v, (M << 10) | 0x1F);
}

#define ALLGATHER16(sv, p) do { \
  sv[0]=bcast16<0>(p);  sv[1]=bcast16<1>(p);  sv[2]=bcast16<2>(p);  sv[3]=bcast16<3>(p);  \
  sv[4]=bcast16<4>(p);  sv[5]=bcast16<5>(p);  sv[6]=bcast16<6>(p);  sv[7]=bcast16<7>(p);  \
  sv[8]=bcast16<8>(p);  sv[9]=bcast16<9>(p);  sv[10]=bcast16<10>(p); sv[11]=bcast16<11>(p); \
  sv[12]=bcast16<12>(p); sv[13]=bcast16<13>(p); sv[14]=bcast16<14>(p); sv[15]=bcast16<15>(p); \
} while (0)

#define SUM16(s) do { s += xshf16<1>(s); s += xshf16<2>(s); s += xshf16<4>(s); s += xshf16<8>(s); } while (0)

// ---------- mask -> lengths (handles byte-bool OR int32 mask storage; mask[0][0] is always true) ----------
__global__ void len_kernel(const void* __restrict__ maskp, int* __restrict__ lens) {
  const int b = blockIdx.x;
  const int l = threadIdx.x;
  const int isInt = (((const int*)maskp)[0] == 1);  // byte storage would read 0x01010101 here
  int cnt = 0;
  if (isInt) {
    const int* m = (const int*)maskp + b * T_;
    for (int t = l; t < T_; t += 64) cnt += (m[t] != 0);
  } else {
    const unsigned char* m = (const unsigned char*)maskp + b * T_;
    for (int t = l; t < T_; t += 64) cnt += (m[t] != 0);
  }
#pragma unroll
  for (int s = 1; s < 64; s <<= 1) cnt += __shfl_xor(cnt, s);
  if (l == 0) lens[b] = cnt;
}

// ---------- emissions: logits[b][t][k] = dot(H[b][t][:], W[k][:]) + bias[k], stored as emis[t][b][k] ----------
__global__ __launch_bounds__(256) void emis_kernel(const float* __restrict__ H,
                                                   const float* __restrict__ W,
                                                   const float* __restrict__ bias,
                                                   float* __restrict__ emis) {
  __shared__ float Wt[D_ * K_];  // [d][k], 32 KB; reads are wave-uniform -> broadcast, conflict-free
  for (int idx = threadIdx.x; idx < D_ * K_; idx += 256) {
    int k = idx >> 9;        // W is (K, D) row-major
    int d = idx & (D_ - 1);
    Wt[d * K_ + k] = W[idx];
  }
  __syncthreads();
  const int r = blockIdx.x * 256 + threadIdx.x;  // row into (B*T)
  const float4* hrow = (const float4*)(H + (size_t)r * D_);
  float acc[16];
#pragma unroll
  for (int k = 0; k < 16; ++k) acc[k] = bias[k];
  float4 a[8], an[8];
#pragma unroll
  for (int u = 0; u < 8; ++u) a[u] = hrow[u];
  for (int c = 0; c < 16; ++c) {          // 16 chunks of 32 dims
    if (c < 15) {
#pragma unroll
      for (int u = 0; u < 8; ++u) an[u] = hrow[(c + 1) * 8 + u];  // prefetch next chunk under FMAs
    }
#pragma unroll
    for (int u = 0; u < 8; ++u) {
#pragma unroll
      for (int q = 0; q < 4; ++q) {
        const int d = c * 32 + u * 4 + q;
        const float4* wr = (const float4*)(Wt + d * K_);
        float x = (q == 0) ? a[u].x : (q == 1) ? a[u].y : (q == 2) ? a[u].z : a[u].w;
        float4 w0 = wr[0], w1 = wr[1], w2 = wr[2], w3 = wr[3];
        acc[0]  = fmaf(x, w0.x, acc[0]);  acc[1]  = fmaf(x, w0.y, acc[1]);
        acc[2]  = fmaf(x, w0.z, acc[2]);  acc[3]  = fmaf(x, w0.w, acc[3]);
        acc[4]  = fmaf(x, w1.x, acc[4]);  acc[5]  = fmaf(x, w1.y, acc[5]);
        acc[6]  = fmaf(x, w1.z, acc[6]);  acc[7]  = fmaf(x, w1.w, acc[7]);
        acc[8]  = fmaf(x, w2.x, acc[8]);  acc[9]  = fmaf(x, w2.y, acc[9]);
        acc[10] = fmaf(x, w2.z, acc[10]); acc[11] = fmaf(x, w2.w, acc[11]);
        acc[12] = fmaf(x, w3.x, acc[12]); acc[13] = fmaf(x, w3.y, acc[13]);
        acc[14] = fmaf(x, w3.z, acc[14]); acc[15] = fmaf(x, w3.w, acc[15]);
      }
    }
#pragma unroll
    for (int u = 0; u < 8; ++u) a[u] = an[u];
  }
  const int b = r >> 10;          // T_ = 1024
  const int t = r & (T_ - 1);
  float4* o = (float4*)(emis + ((size_t)t * B_ + b) * K_);
  o[0] = make_float4(acc[0], acc[1], acc[2], acc[3]);
  o[1] = make_float4(acc[4], acc[5], acc[6], acc[7]);
  o[2] = make_float4(acc[8], acc[9], acc[10], acc[11]);
  o[3] = make_float4(acc[12], acc[13], acc[14], acc[15]);
}

// ---------- CRF: blocks 0-31 logZ, 32-63 viterbi fwd, 64-95 numerator. 64 thr = 4 batches x 16 states ----------
__global__ void crf_kernel(const float* __restrict__ emis, const float* __restrict__ trans,
                           const float* __restrict__ start, const float* __restrict__ endv,
                           const int* __restrict__ labels, const int* __restrict__ lens,
                           float* __restrict__ logZ, unsigned char* __restrict__ hist,
                           int* __restrict__ best, float* __restrict__ num) {
  const int role = blockIdx.x >> 5;
  const int blk  = blockIdx.x & 31;
  const int lane = threadIdx.x;
  const int j = lane & 15;
  const int b = blk * 4 + (lane >> 4);
  const int len = lens[b];

  if (role == 0) {
    // ---- logZ in probability domain: score_j = log(p_j) + c. Normalize every 8 steps only. ----
    float Tc[16];
#pragma unroll
    for (int i = 0; i < 16; ++i) Tc[i] = __expf(trans[i * K_ + j]);  // column j of exp(trans)
    float p = __expf(start[j] + emis[b * K_ + j]);                   // t=0, |score0|<~3.5, safe
    float c = 0.0f;
    float e_next = emis[(B_ + b) * K_ + j];
    for (int t = 1; t < T_; ++t) {
      float e = e_next;
      if (t + 1 < T_) e_next = emis[((t + 1) * B_ + b) * K_ + j];  // prefetch off the chain
      float sv[16];
      ALLGATHER16(sv, p);
      float qa = fmaf(sv[0],  Tc[0],  fmaf(sv[1],  Tc[1],  fmaf(sv[2],  Tc[2],  sv[3]  * Tc[3])));
      float qb = fmaf(sv[4],  Tc[4],  fmaf(sv[5],  Tc[5],  fmaf(sv[6],  Tc[6],  sv[7]  * Tc[7])));
      float qc = fmaf(sv[8],  Tc[8],  fmaf(sv[9],  Tc[9],  fmaf(sv[10], Tc[10], sv[11] * Tc[11])));
      float qd = fmaf(sv[12], Tc[12], fmaf(sv[13], Tc[13], fmaf(sv[14], Tc[14], sv[15] * Tc[15])));
      float q = (qa + qb) + (qc + qd);
      q *= __expf(e);
      p = (t < len) ? q : p;        // masked step keeps old state (score invariant preserved)
      if ((t & 7) == 0) {           // growth <= e^2.8/step, 8 steps safely inside f32 range
        float S = p;
        SUM16(S);
        c += __logf(S);
        p *= __fdividef(1.0f, S);
      }
    }
    float u = p * __expf(endv[j]);
    SUM16(u);
    if (j == 0) logZ[b] = c + __logf(u);
  } else if (role == 1) {
    // ---- Viterbi forward (max-plus), byte history ----
    float Tc[16];
#pragma unroll
    for (int i = 0; i < 16; ++i) Tc[i] = trans[i * K_ + j];
    float s = start[j] + emis[b * K_ + j];
    float e_next = emis[(B_ + b) * K_ + j];
    for (int t = 1; t < T_; ++t) {
      float e = e_next;
      if (t + 1 < T_) e_next = emis[((t + 1) * B_ + b) * K_ + j];
      float sv[16];
      ALLGATHER16(sv, s);
      float tv[16]; int ti[16];
#pragma unroll
      for (int i = 0; i < 16; ++i) { tv[i] = sv[i] + Tc[i]; ti[i] = i; }
#pragma unroll
      for (int st = 8; st >= 1; st >>= 1) {   // tournament, keeps LOWER index on ties (jnp.argmax)
#pragma unroll
        for (int i = 0; i < st; ++i) {
          bool cgt = tv[i + st] > tv[i];
          tv[i] = cgt ? tv[i + st] : tv[i];
          ti[i] = cgt ? ti[i + st] : ti[i];
        }
      }
      hist[t * (B_ * K_) + b * K_ + j] = (unsigned char)ti[0];
      float nxt = tv[0] + e;
      s = (t < len) ? nxt : s;
    }
    float v = s + endv[j];
    int idx = j;
    { float ov = xshf16<1>(v); int oi = xshf16i<1>(idx); bool tk = (ov > v) || ((ov == v) && (oi < idx)); v = tk ? ov : v; idx = tk ? oi : idx; }
    { float ov = xshf16<2>(v); int oi = xshf16i<2>(idx); bool tk = (ov > v) || ((ov == v) && (oi < idx)); v = tk ? ov : v; idx = tk ? oi : idx; }
    { float ov = xshf16<4>(v); int oi = xshf16i<4>(idx); bool tk = (ov > v) || ((ov == v) && (oi < idx)); v = tk ? ov : v; idx = tk ? oi : idx; }
    { float ov = xshf16<8>(v); int oi = xshf16i<8>(idx); bool tk = (ov > v) || ((ov == v) && (oi < idx)); v = tk ? ov : v; idx = tk ? oi : idx; }
    if (j == 0) best[b] = idx;
  } else {
    // ---- numerator: gather-sum, 16 lanes stride over t ----
    const int* lab = labels + b * T_;
    float acc = 0.0f;
    for (int t = j; t < T_; t += 16) {
      int lt = lab[t];
      float e = emis[(t * B_ + b) * K_ + lt];
      if (t == 0) acc += start[lt] + e;                       // t=0 term is unmasked in reference
      else if (t < len) acc += trans[lab[t - 1] * K_ + lt] + e;
    }
    SUM16(acc);
    if (j == 0) num[b] = acc + endv[lab[len - 1]];
  }
}

// ---------- backtrack (blocks 0-31) + loss (block 32) ----------
__global__ void bt_kernel(const unsigned char* __restrict__ hist, const int* __restrict__ best,
                          const int* __restrict__ lens, const float* __restrict__ num,
                          const float* __restrict__ logZ, float* __restrict__ out) {
  if (blockIdx.x == 32) {
    int l = threadIdx.x;
    float s = (num[l] - logZ[l]) + (num[l + 64] - logZ[l + 64]);
#pragma unroll
    for (int m = 1; m < 64; m <<= 1) s += __shfl_xor(s, m);
    if (l == 0) out[B_ * T_] = -s / (float)B_;
    return;
  }
  const int lane = threadIdx.x;
  const int l = lane & 15;
  const int b = blockIdx.x * 4 + (lane >> 4);
  const int len = lens[b];
  int cur = best[b];                                   // replicated across the 16-lane group
  int hb = hist[1023 * (B_ * K_) + b * K_ + l];        // lane l holds hist[t][b][l]
  for (int t = 1023; t >= 1; --t) {
    int h = hb;
    if (t > 1) hb = hist[(t - 1) * (B_ * K_) + b * K_ + l];  // prefetch; only the shfl is on the chain
    bool m = (t < len);
    if (l == 0) out[b * T_ + t] = m ? (float)cur : 0.0f;     // tag BEFORE stepping (matches reference)
    int prev = __shfl(h, (lane & 48) | cur);
    cur = m ? prev : cur;
  }
  if (l == 0) out[b * T_] = (float)cur;
}

extern "C" void kernel_launch(void* const* d_in, const int* in_sizes, int n_in,
                              void* d_out, int out_size, void* d_ws, size_t ws_size,
                              hipStream_t stream) {
  const float* H      = (const float*)d_in[0];
  const void*  maskp  = d_in[1];
  const int*   labels = (const int*)d_in[2];
  const float* W      = (const float*)d_in[3];
  const float* bias   = (const float*)d_in[4];
  const float* start  = (const float*)d_in[5];
  const float* trans  = (const float*)d_in[6];
  const float* endv   = (const float*)d_in[7];

  char* ws = (char*)d_ws;
  float*         emis = (float*)ws;                          //  8 MB  emis[t][b][k]
  unsigned char* hist = (unsigned char*)(ws + 8388608);      //  2 MB  hist[t][b][j]
  float*         num  = (float*)(ws + 10485760);             //  512 B
  float*         logZ = (float*)(ws + 10486272);             //  512 B
  int*           best = (int*)(ws + 10486784);               //  512 B
  int*           lens = (int*)(ws + 10487296);               //  512 B
  float*         out  = (float*)d_out;                       //  pred (B*T floats) then loss

  len_kernel<<<dim3(B_), dim3(64), 0, stream>>>(maskp, lens);
  emis_kernel<<<dim3((B_ * T_) / 256), dim3(256), 0, stream>>>(H, W, bias, emis);
  crf_kernel<<<dim3(96), dim3(64), 0, stream>>>(emis, trans, start, endv, labels, lens,
                                                logZ, hist, best, num);
  bt_kernel<<<dim3(33), dim3(64), 0, stream>>>(hist, best, lens, num, logZ, out);
}